// Round 3
// baseline (344.717 us; speedup 1.0000x reference)
//
#include <hip/hip_runtime.h>

#define NH 64

typedef _Float16 half8 __attribute__((ext_vector_type(8)));
typedef float float4v __attribute__((ext_vector_type(4)));

__device__ __forceinline__ float fast_tanh(float x) {
  float ax = fabsf(x);
  float e  = __expf(-2.0f * ax);
  float y  = (1.0f - e) * __builtin_amdgcn_rcpf(1.0f + e);
  return copysignf(y, x);
}

// B_k[h][j] = mono_k(h) * W2[h][j], packed in MFMA B-fragment lane order for
// v_mfma_f32_16x16x32_f16:  B[k_in=quad*8+jj + 32*ks][n=col],  lane=quad*16+col.
// Slot layout (half units): frag(slot,nt,ks) at ((slot*4+nt)*2+ks)*512 + lane*8 + jj.
// Slots 0..9 = hi parts of the 10 kinds; slots 10..12 = lo parts of kinds 0..2.
// Kinds: 0:z0(y)  1:zp(f1*a) 2:zt(f1*b) 3:zpp(f2*a^2) 4:zpt(f2*ab) 5:ztt(f2*b^2)
//        6:zppp(f3*a^3) 7:zppt(f3*a^2b) 8:zptt(f3*ab^2) 9:zttt(f3*b^3)
// The -2 of tanh'' is folded into kinds 3..5 (A-side supplies f2a = y*f1).
//
// The whole 104 KB table now lives in LDS, built once per block (fused old
// prep_B); every block loops over tiles so B-fragment reads are ds_read_b128
// from LDS instead of ~200-cycle L2 loads (the round-0 latency bottleneck:
// MfmaUtil 9.7 / VALUBusy 36 / HBM 2% = ~55% exposed latency).
//
// 512 threads = 8 waves; LDS 104 KB caps at 1 block/CU -> 2 waves/SIMD,
// which is the occupancy the register budget wants anyway: waves_per_eu(2,2)
// gives the 256-VGPR budget this kernel's ~124-VGPR live state needs.
// ((4) and (4,4) both made the allocator target 64 arch VGPRs and spill
// ~480 MB/dispatch to scratch: 68us -> 150us. Do not raise this.)
__global__ __launch_bounds__(512) __attribute__((amdgpu_waves_per_eu(2, 2)))
void pinn_mfma(
    const float* __restrict__ phi, const float* __restrict__ theta,
    const float* __restrict__ radius, const float* __restrict__ hth,
    const float* __restrict__ hph, const float* __restrict__ br,
    const float* __restrict__ W1, const float* __restrict__ b1,
    const float* __restrict__ W2, const float* __restrict__ b2,
    const float* __restrict__ W3, float* __restrict__ out, int n) {
  __shared__ _Float16 Bs[13 * 4096];   // 104 KB

  // ---- build B table into LDS (bit-identical to the old prep_B) ----
  for (int i = threadIdx.x; i < 13 * 4096; i += 512) {
    int s = i >> 12;                 // slot 0..12
    int off = i & 4095;              // offset within slot
    int nt = off >> 10;
    int ks = (off >> 9) & 1;
    int ln = (off >> 3) & 63;
    int jj = off & 7;
    int h = ks * 32 + (ln >> 4) * 8 + jj;
    int j = nt * 16 + (ln & 15);
    float a = W1[h], b = W1[NH + h];
    float w2 = W2[h * NH + j];
    int kind = (s < 10) ? s : (s - 10);
    float mono;
    switch (kind) {
      case 0: mono = 1.0f; break;
      case 1: mono = a; break;
      case 2: mono = b; break;
      case 3: mono = -2.0f * a * a; break;
      case 4: mono = -2.0f * a * b; break;
      case 5: mono = -2.0f * b * b; break;
      case 6: mono = a * a * a; break;
      case 7: mono = a * a * b; break;
      case 8: mono = a * b * b; break;
      default: mono = b * b * b; break;
    }
    float v = mono * w2;
    _Float16 hi = (_Float16)v;
    Bs[i] = (s < 10) ? hi : (_Float16)(v - (float)hi);
  }
  __syncthreads();

  const int lane = threadIdx.x & 63;
  const int wave = threadIdx.x >> 6;
  const int quad = lane >> 4, col = lane & 15;
  const int ntiles = (n + 15) >> 4;
  const int wstride = gridDim.x * 8;

  for (int tile = blockIdx.x * 8 + wave; tile < ntiles; tile += wstride) {
    const int pbase = tile * 16;

    // ---- A-fragments: lane's point m=col, h = 32*ks + quad*8 + jj ----
    float p = phi[pbase + col], t = theta[pbase + col];
    half8 aYh[2], aYl[2], aF1h[2], aF1l[2], aF2[2], aF3[2];
#pragma unroll
    for (int ks = 0; ks < 2; ++ks) {
#pragma unroll
      for (int jj = 0; jj < 8; ++jj) {
        int h = ks * 32 + quad * 8 + jj;
        float z = fmaf(p, W1[h], fmaf(t, W1[NH + h], b1[h]));
        float y = fast_tanh(z);
        float f1 = fmaf(-y, y, 1.0f);
        float f2a = y * f1;                     // true f2 = -2*y*f1; -2 folded into B
        float f3 = f1 * fmaf(-6.0f, f1, 4.0f);
        _Float16 yh = (_Float16)y;
        _Float16 f1h = (_Float16)f1;
        aYh[ks][jj] = yh;   aYl[ks][jj] = (_Float16)(y - (float)yh);
        aF1h[ks][jj] = f1h; aF1l[ks][jj] = (_Float16)(f1 - (float)f1h);
        aF2[ks][jj] = (_Float16)f2a;
        aF3[ks][jj] = (_Float16)f3;
      }
    }

    float4v Tacc[9];
#pragma unroll
    for (int x = 0; x < 9; ++x) Tacc[x] = (float4v){0.f, 0.f, 0.f, 0.f};

#pragma unroll
    for (int nt = 0; nt < 4; ++nt) {
      float4v acc[10];
#pragma unroll
      for (int k = 0; k < 10; ++k) acc[k] = (float4v){0.f, 0.f, 0.f, 0.f};
#pragma unroll
      for (int ks = 0; ks < 2; ++ks) {
#pragma unroll
        for (int k = 0; k < 10; ++k) {
          half8 ah = (k == 0) ? aYh[ks] : (k < 3) ? aF1h[ks] : (k < 6) ? aF2[ks] : aF3[ks];
          half8 bh = *(const half8*)(Bs + ((k * 4 + nt) * 2 + ks) * 512 + lane * 8);
          acc[k] = __builtin_amdgcn_mfma_f32_16x16x32_f16(ah, bh, acc[k], 0, 0, 0);
          if (k < 3) {
            half8 al = (k == 0) ? aYl[ks] : aF1l[ks];
            acc[k] = __builtin_amdgcn_mfma_f32_16x16x32_f16(al, bh, acc[k], 0, 0, 0);
            half8 bl = *(const half8*)(Bs + (((10 + k) * 4 + nt) * 2 + ks) * 512 + lane * 8);
            acc[k] = __builtin_amdgcn_mfma_f32_16x16x32_f16(ah, bl, acc[k], 0, 0, 0);
          }
        }
      }
      // ---- Faa di Bruno + W3 on C-layout: lane holds (point=quad*4+r, j=nt*16+col) ----
      float b2v = b2[nt * 16 + col];
      float w3v = W3[nt * 16 + col];
#pragma unroll
      for (int r = 0; r < 4; ++r) {
        float z0 = acc[0][r] + b2v;
        float y2 = fast_tanh(z0);
        float g1 = fmaf(-y2, y2, 1.0f);
        float g2 = -2.0f * (y2 * g1);
        float g3 = g1 * fmaf(-6.0f, g1, 4.0f);
        float gp = acc[1][r], gt = acc[2][r];
        float gpp = acc[3][r], gpt = acc[4][r], gtt = acc[5][r];
        float zppp = acc[6][r], zppt = acc[7][r], zptt = acc[8][r], zttt = acc[9][r];
        float gp2 = gp * gp, gt2 = gt * gt;
        Tacc[0][r] = fmaf(w3v, g1 * gp, Tacc[0][r]);
        Tacc[1][r] = fmaf(w3v, g1 * gt, Tacc[1][r]);
        Tacc[2][r] = fmaf(w3v, fmaf(g2, gp2, g1 * gpp), Tacc[2][r]);
        Tacc[3][r] = fmaf(w3v, fmaf(g2, gp * gt, g1 * gpt), Tacc[3][r]);
        Tacc[4][r] = fmaf(w3v, fmaf(g2, gt2, g1 * gtt), Tacc[4][r]);
        Tacc[5][r] = fmaf(w3v, fmaf(g3, gp2 * gp, fmaf(3.0f * g2, gp * gpp, g1 * zppp)), Tacc[5][r]);
        Tacc[6][r] = fmaf(w3v, fmaf(g3, gp2 * gt, fmaf(g2, fmaf(2.0f, gp * gpt, gt * gpp), g1 * zppt)), Tacc[6][r]);
        Tacc[7][r] = fmaf(w3v, fmaf(g3, gp * gt2, fmaf(g2, fmaf(2.0f, gt * gpt, gp * gtt), g1 * zptt)), Tacc[7][r]);
        Tacc[8][r] = fmaf(w3v, fmaf(g3, gt2 * gt, fmaf(3.0f * g2, gt * gtt, g1 * zttt)), Tacc[8][r]);
      }
    }

    // ---- reduce over j: butterfly across the 16 cols (same quad group) ----
#pragma unroll
    for (int x = 0; x < 9; ++x) {
#pragma unroll
      for (int r = 0; r < 4; ++r) {
        float v = Tacc[x][r];
        v += __shfl_xor(v, 1, 16);
        v += __shfl_xor(v, 2, 16);
        v += __shfl_xor(v, 4, 16);
        v += __shfl_xor(v, 8, 16);
        Tacc[x][r] = v;
      }
    }

    // lane handles point = quad*4 + (col&3); lanes col<4 store.
    int rsel = col & 3;
    float T[9];
#pragma unroll
    for (int x = 0; x < 9; ++x) {
      float4v v = Tacc[x];
      T[x] = (rsel == 0) ? v[0] : (rsel == 1) ? v[1] : (rsel == 2) ? v[2] : v[3];
    }
    float Tp = T[0], Tt = T[1], Tpp = T[2], Tpt = T[3], Ttt = T[4];
    float Tppp = T[5], Tppt = T[6], Tptt = T[7], Tttt = T[8];

    int pi = pbase + quad * 4 + rsel;
    float t2 = theta[pi];
    float s = sinf(t2), c = cosf(t2);
    float inv_s = 1.0f / s;
    float inv_s2 = inv_s * inv_s;

    float A = Tp * inv_s + Tt;          // u_theta
    float D = Tp * inv_s - Tt;          // u_phi
    float q1 = Tpt * inv_s - Tp * c * inv_s2;
    float A_t = q1 + Ttt;
    float D_t = q1 - Ttt;
    float q2 = Tptt * inv_s - 2.0f * Tpt * c * inv_s2
             + Tp * (s * s + 2.0f * c * c) * inv_s2 * inv_s;
    float A_tt = q2 + Tttt;
    float D_tt = q2 - Tttt;
    float A_pp = Tppp * inv_s + Tppt;
    float D_p  = Tpp * inv_s - Tpt;
    float D_pp = Tppp * inv_s - Tppt;

    float utt   = -(A_t * s + A * c);
    float uttt  = -(A_tt * s + 2.0f * A_t * c - A * s) * s + utt * c;
    float utpp  = -A_pp;
    float upht  = D_t * s + D * c;
    float uphtt = (D_tt * s + 2.0f * D_t * c - D * s) * s + upht * c;
    float upp   = D_p;
    float uppp  = D_pp;

    float r = radius[pi];
    float inv_r = 1.0f / r;
    float inv_r2 = inv_r * inv_r;
    float div_uh = (utt + upp) * inv_r * inv_s;
    float lap_t = s * inv_r2 * uttt + utpp * inv_s2 * inv_r2;
    float lap_p = s * inv_r2 * uphtt + uppp * inv_s2 * inv_r2;
    float comp = s * (lap_t * lap_t + lap_p * lap_p);
    float sv = -(A * hth[pi] + D * hph[pi]) - br[pi] * div_uh;
    float tg = div_uh - A * (s / c) * inv_r;

    if (col < 4) {
      out[pi]         = A;
      out[n + pi]     = D;
      out[2 * n + pi] = div_uh;
      out[3 * n + pi] = sv;
      out[4 * n + pi] = tg;
      out[5 * n + pi] = comp;
    }
  }
}

extern "C" void kernel_launch(void* const* d_in, const int* in_sizes, int n_in,
                              void* d_out, int out_size, void* d_ws, size_t ws_size,
                              hipStream_t stream) {
  const float* phi    = (const float*)d_in[0];
  const float* theta  = (const float*)d_in[1];
  const float* radius = (const float*)d_in[2];
  const float* hth    = (const float*)d_in[3];
  const float* hph    = (const float*)d_in[4];
  const float* br     = (const float*)d_in[5];
  const float* W1     = (const float*)d_in[6];
  const float* b1     = (const float*)d_in[7];
  const float* W2     = (const float*)d_in[8];
  const float* b2     = (const float*)d_in[9];
  const float* W3     = (const float*)d_in[10];
  (void)ws_size; (void)n_in; (void)out_size; (void)d_ws;

  float* out = (float*)d_out;
  int n = in_sizes[0];

  int ntiles = (n + 15) / 16;
  int nblocks = (ntiles + 7) / 8;
  if (nblocks > 256) nblocks = 256;     // 1 block/CU (LDS-capped anyway)
  pinn_mfma<<<nblocks, 512, 0, stream>>>(
      phi, theta, radius, hth, hph, br, W1, b1, W2, b2, W3, out, n);
}

// Round 4
// 113.245 us; speedup vs baseline: 3.0440x; 3.0440x over previous
//
#include <hip/hip_runtime.h>

#define NH 64

typedef _Float16 half8 __attribute__((ext_vector_type(8)));
typedef float float4v __attribute__((ext_vector_type(4)));

__device__ __forceinline__ float fast_tanh(float x) {
  float ax = fabsf(x);
  float e  = __expf(-2.0f * ax);
  float y  = (1.0f - e) * __builtin_amdgcn_rcpf(1.0f + e);
  return copysignf(y, x);
}

// NEW DECOMPOSITION: mono_k(h) depends only on h (the MFMA K-dim), so it is
// folded into the A side. B is now just W2 packed in MFMA B-fragment lane
// order, split hi/lo f16:  slot 0 = (f16)W2, slot 1 = (f16)(W2 - hi).
// Table = 2 slots * 4 nt * 2 ks * 512 halfs = 16 KB -> fits L1; every tile's
// B loads are L1 hits instead of the ~200-cycle L2 reads that made round-0
// latency-bound (MfmaUtil 9.7 / VALUBusy 36 / HBM 2% at 68us).
// frag(s,nt,ks) at (s*8 + nt*2 + ks)*512 + lane*8 + jj, lane = quad*16+col,
// element (k_in = quad*8+jj + 32*ks, n = nt*16+col).
__global__ void prep_B(const float* __restrict__ W2, _Float16* __restrict__ ws) {
  int i = blockIdx.x * 256 + threadIdx.x;
  if (i >= 2 * 4096) return;
  int s = i >> 12;                 // 0 = hi, 1 = lo
  int off = i & 4095;
  int nt = off >> 10;
  int ks = (off >> 9) & 1;
  int ln = (off >> 3) & 63;
  int jj = off & 7;
  int h = ks * 32 + (ln >> 4) * 8 + jj;
  int j = nt * 16 + (ln & 15);
  float w2 = W2[h * NH + j];
  _Float16 hi = (_Float16)w2;
  ws[(s * 8 + nt * 2 + ks) * 512 + ln * 8 + jj] =
      (s == 0) ? hi : (_Float16)(w2 - (float)hi);
}

__device__ __forceinline__ half8 ldB(const _Float16* ws, int s, int nt, int ks, int lane) {
  return *(const half8*)(ws + (s * 8 + nt * 2 + ks) * 512 + lane * 8);
}

// 256 threads = 4 waves; wave w handles point-tile blockIdx*4+w (16 points).
// MFMA 16x16x32 f16: M=16 points, N=64 j (4 ntiles), K=64 h (2 ksteps).
// A-side kinds (per h, folded mono):
//  0: y (hi/lo)   1: f1*a (hi/lo)   2: f1*b (hi/lo)
//  3: yf1*(-2a^2) 4: yf1*(-2ab) 5: yf1*(-2b^2)
//  6: f3*a^3 7: f3*a^2*b 8: f3*a*b^2 9: f3*b^3      (f3 = f1*(4-6*f1))
// hi/lo product split (3 MFMAs) on kinds 0..2; hi-only on kinds 3..9.
//
// waves_per_eu(2,2): ~208 total regs (132 arch + 76 accum) needs the
// 256-reg/2-waves-per-EU budget. (4)/(4,4)/512-thr-loop variants all spilled
// ~0.5 GB/dispatch to scratch (68us -> 150-270us). Keep this structure.
__global__ __launch_bounds__(256) __attribute__((amdgpu_waves_per_eu(2, 2)))
void pinn_mfma(
    const float* __restrict__ phi, const float* __restrict__ theta,
    const float* __restrict__ radius, const float* __restrict__ hth,
    const float* __restrict__ hph, const float* __restrict__ br,
    const float* __restrict__ W1, const float* __restrict__ b1,
    const float* __restrict__ b2, const float* __restrict__ W3,
    const _Float16* __restrict__ Bws, float* __restrict__ out, int n) {
  const int lane = threadIdx.x & 63;
  const int wave = threadIdx.x >> 6;
  const int tile = blockIdx.x * 4 + wave;
  const int quad = lane >> 4, col = lane & 15;
  const int pbase = tile * 16;
  if (pbase >= n) return;

  // ---- A-fragments: lane's point m=col, h = 32*ks + quad*8 + jj ----
  float p = phi[pbase + col], t = theta[pbase + col];
  half8 A0h[2], A0l[2], A1h[2], A1l[2], A2h[2], A2l[2];
  half8 A3[2], A4[2], A5[2], A6[2], A7[2], A8[2], A9[2];
#pragma unroll
  for (int ks = 0; ks < 2; ++ks) {
#pragma unroll
    for (int jj = 0; jj < 8; ++jj) {
      int h = ks * 32 + quad * 8 + jj;
      float a = W1[h], b = W1[NH + h];
      float z = fmaf(p, a, fmaf(t, b, b1[h]));
      float y = fast_tanh(z);
      float f1 = fmaf(-y, y, 1.0f);
      float f2a = y * f1;                       // true f2 = -2*y*f1; -2 in monos
      float f3 = f1 * fmaf(-6.0f, f1, 4.0f);
      float a2 = a * a, ab = a * b, b2v_ = b * b;
      float v1 = f1 * a, v2 = f1 * b;
      _Float16 yh = (_Float16)y;
      _Float16 v1h = (_Float16)v1;
      _Float16 v2h = (_Float16)v2;
      A0h[ks][jj] = yh;   A0l[ks][jj] = (_Float16)(y - (float)yh);
      A1h[ks][jj] = v1h;  A1l[ks][jj] = (_Float16)(v1 - (float)v1h);
      A2h[ks][jj] = v2h;  A2l[ks][jj] = (_Float16)(v2 - (float)v2h);
      A3[ks][jj] = (_Float16)(f2a * (-2.0f * a2));
      A4[ks][jj] = (_Float16)(f2a * (-2.0f * ab));
      A5[ks][jj] = (_Float16)(f2a * (-2.0f * b2v_));
      A6[ks][jj] = (_Float16)(f3 * (a2 * a));
      A7[ks][jj] = (_Float16)(f3 * (a2 * b));
      A8[ks][jj] = (_Float16)(f3 * (a * b2v_));
      A9[ks][jj] = (_Float16)(f3 * (b2v_ * b));
    }
  }

  float4v Tacc[9];
#pragma unroll
  for (int x = 0; x < 9; ++x) Tacc[x] = (float4v){0.f, 0.f, 0.f, 0.f};

#pragma unroll
  for (int nt = 0; nt < 4; ++nt) {
    float4v acc[10];
#pragma unroll
    for (int k = 0; k < 10; ++k) acc[k] = (float4v){0.f, 0.f, 0.f, 0.f};
#pragma unroll
    for (int ks = 0; ks < 2; ++ks) {
      half8 bh = ldB(Bws, 0, nt, ks, lane);
      half8 bl = ldB(Bws, 1, nt, ks, lane);
      acc[0] = __builtin_amdgcn_mfma_f32_16x16x32_f16(A0h[ks], bh, acc[0], 0, 0, 0);
      acc[0] = __builtin_amdgcn_mfma_f32_16x16x32_f16(A0l[ks], bh, acc[0], 0, 0, 0);
      acc[0] = __builtin_amdgcn_mfma_f32_16x16x32_f16(A0h[ks], bl, acc[0], 0, 0, 0);
      acc[1] = __builtin_amdgcn_mfma_f32_16x16x32_f16(A1h[ks], bh, acc[1], 0, 0, 0);
      acc[1] = __builtin_amdgcn_mfma_f32_16x16x32_f16(A1l[ks], bh, acc[1], 0, 0, 0);
      acc[1] = __builtin_amdgcn_mfma_f32_16x16x32_f16(A1h[ks], bl, acc[1], 0, 0, 0);
      acc[2] = __builtin_amdgcn_mfma_f32_16x16x32_f16(A2h[ks], bh, acc[2], 0, 0, 0);
      acc[2] = __builtin_amdgcn_mfma_f32_16x16x32_f16(A2l[ks], bh, acc[2], 0, 0, 0);
      acc[2] = __builtin_amdgcn_mfma_f32_16x16x32_f16(A2h[ks], bl, acc[2], 0, 0, 0);
      acc[3] = __builtin_amdgcn_mfma_f32_16x16x32_f16(A3[ks], bh, acc[3], 0, 0, 0);
      acc[4] = __builtin_amdgcn_mfma_f32_16x16x32_f16(A4[ks], bh, acc[4], 0, 0, 0);
      acc[5] = __builtin_amdgcn_mfma_f32_16x16x32_f16(A5[ks], bh, acc[5], 0, 0, 0);
      acc[6] = __builtin_amdgcn_mfma_f32_16x16x32_f16(A6[ks], bh, acc[6], 0, 0, 0);
      acc[7] = __builtin_amdgcn_mfma_f32_16x16x32_f16(A7[ks], bh, acc[7], 0, 0, 0);
      acc[8] = __builtin_amdgcn_mfma_f32_16x16x32_f16(A8[ks], bh, acc[8], 0, 0, 0);
      acc[9] = __builtin_amdgcn_mfma_f32_16x16x32_f16(A9[ks], bh, acc[9], 0, 0, 0);
    }
    // ---- Faa di Bruno + W3 on C-layout: lane holds (point=quad*4+r, j=nt*16+col) ----
    float b2v = b2[nt * 16 + col];
    float w3v = W3[nt * 16 + col];
#pragma unroll
    for (int r = 0; r < 4; ++r) {
      float z0 = acc[0][r] + b2v;
      float y2 = fast_tanh(z0);
      float g1 = fmaf(-y2, y2, 1.0f);
      float g2 = -2.0f * (y2 * g1);
      float g3 = g1 * fmaf(-6.0f, g1, 4.0f);
      float gp = acc[1][r], gt = acc[2][r];
      float gpp = acc[3][r], gpt = acc[4][r], gtt = acc[5][r];
      float zppp = acc[6][r], zppt = acc[7][r], zptt = acc[8][r], zttt = acc[9][r];
      float gp2 = gp * gp, gt2 = gt * gt;
      Tacc[0][r] = fmaf(w3v, g1 * gp, Tacc[0][r]);
      Tacc[1][r] = fmaf(w3v, g1 * gt, Tacc[1][r]);
      Tacc[2][r] = fmaf(w3v, fmaf(g2, gp2, g1 * gpp), Tacc[2][r]);
      Tacc[3][r] = fmaf(w3v, fmaf(g2, gp * gt, g1 * gpt), Tacc[3][r]);
      Tacc[4][r] = fmaf(w3v, fmaf(g2, gt2, g1 * gtt), Tacc[4][r]);
      Tacc[5][r] = fmaf(w3v, fmaf(g3, gp2 * gp, fmaf(3.0f * g2, gp * gpp, g1 * zppp)), Tacc[5][r]);
      Tacc[6][r] = fmaf(w3v, fmaf(g3, gp2 * gt, fmaf(g2, fmaf(2.0f, gp * gpt, gt * gpp), g1 * zppt)), Tacc[6][r]);
      Tacc[7][r] = fmaf(w3v, fmaf(g3, gp * gt2, fmaf(g2, fmaf(2.0f, gt * gpt, gp * gtt), g1 * zptt)), Tacc[7][r]);
      Tacc[8][r] = fmaf(w3v, fmaf(g3, gt2 * gt, fmaf(3.0f * g2, gt * gtt, g1 * zttt)), Tacc[8][r]);
    }
  }

  // ---- reduce over j: butterfly across the 16 cols (same quad group) ----
#pragma unroll
  for (int x = 0; x < 9; ++x) {
#pragma unroll
    for (int r = 0; r < 4; ++r) {
      float v = Tacc[x][r];
      v += __shfl_xor(v, 1, 16);
      v += __shfl_xor(v, 2, 16);
      v += __shfl_xor(v, 4, 16);
      v += __shfl_xor(v, 8, 16);
      Tacc[x][r] = v;
    }
  }

  // lane handles point = quad*4 + (col&3); lanes col<4 store.
  int rsel = col & 3;
  float T[9];
#pragma unroll
  for (int x = 0; x < 9; ++x) {
    float4v v = Tacc[x];
    T[x] = (rsel == 0) ? v[0] : (rsel == 1) ? v[1] : (rsel == 2) ? v[2] : v[3];
  }
  float Tp = T[0], Tt = T[1], Tpp = T[2], Tpt = T[3], Ttt = T[4];
  float Tppp = T[5], Tppt = T[6], Tptt = T[7], Tttt = T[8];

  int pi = pbase + quad * 4 + rsel;
  float t2 = theta[pi];
  float s = sinf(t2), c = cosf(t2);
  float inv_s = 1.0f / s;
  float inv_s2 = inv_s * inv_s;

  float A = Tp * inv_s + Tt;          // u_theta
  float D = Tp * inv_s - Tt;          // u_phi
  float q1 = Tpt * inv_s - Tp * c * inv_s2;
  float A_t = q1 + Ttt;
  float D_t = q1 - Ttt;
  float q2 = Tptt * inv_s - 2.0f * Tpt * c * inv_s2
           + Tp * (s * s + 2.0f * c * c) * inv_s2 * inv_s;
  float A_tt = q2 + Tttt;
  float D_tt = q2 - Tttt;
  float A_pp = Tppp * inv_s + Tppt;
  float D_p  = Tpp * inv_s - Tpt;
  float D_pp = Tppp * inv_s - Tppt;

  float utt   = -(A_t * s + A * c);
  float uttt  = -(A_tt * s + 2.0f * A_t * c - A * s) * s + utt * c;
  float utpp  = -A_pp;
  float upht  = D_t * s + D * c;
  float uphtt = (D_tt * s + 2.0f * D_t * c - D * s) * s + upht * c;
  float upp   = D_p;
  float uppp  = D_pp;

  float r = radius[pi];
  float inv_r = 1.0f / r;
  float inv_r2 = inv_r * inv_r;
  float div_uh = (utt + upp) * inv_r * inv_s;
  float lap_t = s * inv_r2 * uttt + utpp * inv_s2 * inv_r2;
  float lap_p = s * inv_r2 * uphtt + uppp * inv_s2 * inv_r2;
  float comp = s * (lap_t * lap_t + lap_p * lap_p);
  float sv = -(A * hth[pi] + D * hph[pi]) - br[pi] * div_uh;
  float tg = div_uh - A * (s / c) * inv_r;

  if (col < 4) {
    out[pi]         = A;
    out[n + pi]     = D;
    out[2 * n + pi] = div_uh;
    out[3 * n + pi] = sv;
    out[4 * n + pi] = tg;
    out[5 * n + pi] = comp;
  }
}

extern "C" void kernel_launch(void* const* d_in, const int* in_sizes, int n_in,
                              void* d_out, int out_size, void* d_ws, size_t ws_size,
                              hipStream_t stream) {
  const float* phi    = (const float*)d_in[0];
  const float* theta  = (const float*)d_in[1];
  const float* radius = (const float*)d_in[2];
  const float* hth    = (const float*)d_in[3];
  const float* hph    = (const float*)d_in[4];
  const float* br     = (const float*)d_in[5];
  const float* W1     = (const float*)d_in[6];
  const float* b1     = (const float*)d_in[7];
  const float* W2     = (const float*)d_in[8];
  const float* b2     = (const float*)d_in[9];
  const float* W3     = (const float*)d_in[10];
  (void)ws_size; (void)n_in; (void)out_size;

  _Float16* Bws = (_Float16*)d_ws;     // 2 slots * 4 nt * 2 ks * 512 halfs = 16 KB
  float* out = (float*)d_out;
  int n = in_sizes[0];

  prep_B<<<(2 * 4096 + 255) / 256, 256, 0, stream>>>(W2, Bws);
  int ntiles = (n + 15) / 16;
  int nblocks = (ntiles + 3) / 4;
  pinn_mfma<<<nblocks, 256, 0, stream>>>(
      phi, theta, radius, hth, hph, br, W1, b1, b2, W3, Bws, out, n);
}

// Round 5
// 110.293 us; speedup vs baseline: 3.1255x; 1.0268x over previous
//
#include <hip/hip_runtime.h>

#define NH 64

typedef _Float16 half8 __attribute__((ext_vector_type(8)));
typedef float float4v __attribute__((ext_vector_type(4)));

__device__ __forceinline__ float fast_tanh(float x) {
  float ax = fabsf(x);
  float e  = __expf(-2.0f * ax);
  float y  = (1.0f - e) * __builtin_amdgcn_rcpf(1.0f + e);
  return copysignf(y, x);
}

// B = W2 packed in MFMA B-fragment lane order, split hi/lo f16:
// slot 0 = (f16)W2, slot 1 = (f16)(W2 - hi).  16 KB total -> L1-resident,
// so per-tile B loads are L1 hits (this was the round-4 win: 68us -> 44us).
// frag(s,nt,ks) at (s*8 + nt*2 + ks)*512 + lane*8 + jj, lane = quad*16+col,
// element (k_in = quad*8+jj + 32*ks, n = nt*16+col).
__global__ void prep_B(const float* __restrict__ W2, _Float16* __restrict__ ws) {
  int i = blockIdx.x * 256 + threadIdx.x;
  if (i >= 2 * 4096) return;
  int s = i >> 12;                 // 0 = hi, 1 = lo
  int off = i & 4095;
  int nt = off >> 10;
  int ks = (off >> 9) & 1;
  int ln = (off >> 3) & 63;
  int jj = off & 7;
  int h = ks * 32 + (ln >> 4) * 8 + jj;
  int j = nt * 16 + (ln & 15);
  float w2 = W2[h * NH + j];
  _Float16 hi = (_Float16)w2;
  ws[(s * 8 + nt * 2 + ks) * 512 + ln * 8 + jj] =
      (s == 0) ? hi : (_Float16)(w2 - (float)hi);
}

__device__ __forceinline__ half8 ldB(const _Float16* ws, int s, int nt, int ks, int lane) {
  return *(const half8*)(ws + (s * 8 + nt * 2 + ks) * 512 + lane * 8);
}

// 256 threads = 4 waves; wave w handles point-tile blockIdx*4+w (16 points).
// MFMA 16x16x32 f16: M=16 points, N=64 j (4 ntiles), K=64 h (2 ksteps).
// A-side kinds (mono_k(h) folded into A since it only depends on the K-dim):
//  0: y (hi/lo)   1: f1*a (hi/lo)   2: f1*b (hi/lo)
//  3..5: yf1*{-2a^2,-2ab,-2b^2}   6..9: f3*{a^3,a^2b,ab^2,b^3}
// hi/lo product split (3 MFMAs) on kinds 0..2; hi-only on kinds 3..9.
//
// waves_per_eu(2,2): ~200 total regs (124 arch + 76 accum) needs the
// 256-reg/2-waves-per-EU budget. (4)/(4,4)/512-thr-loop variants all spilled
// ~0.5 GB/dispatch to scratch (68us -> 150-270us). Keep this structure.
// Kernel is VALU-throughput-bound (VALUBusy 61 / MfmaUtil 15 / HBM 1.4%),
// so this round cuts VALU ops: fold-butterfly reduce, monomial CSE,
// __sincosf + rcpf epilogue.
__global__ __launch_bounds__(256) __attribute__((amdgpu_waves_per_eu(2, 2)))
void pinn_mfma(
    const float* __restrict__ phi, const float* __restrict__ theta,
    const float* __restrict__ radius, const float* __restrict__ hth,
    const float* __restrict__ hph, const float* __restrict__ br,
    const float* __restrict__ W1, const float* __restrict__ b1,
    const float* __restrict__ b2, const float* __restrict__ W3,
    const _Float16* __restrict__ Bws, float* __restrict__ out, int n) {
  const int lane = threadIdx.x & 63;
  const int wave = threadIdx.x >> 6;
  const int tile = blockIdx.x * 4 + wave;
  const int quad = lane >> 4, col = lane & 15;
  const int pbase = tile * 16;
  if (pbase >= n) return;

  // ---- A-fragments: lane's point m=col, h = 32*ks + quad*8 + jj ----
  float p = phi[pbase + col], t = theta[pbase + col];
  half8 A0h[2], A0l[2], A1h[2], A1l[2], A2h[2], A2l[2];
  half8 A3[2], A4[2], A5[2], A6[2], A7[2], A8[2], A9[2];
#pragma unroll
  for (int ks = 0; ks < 2; ++ks) {
#pragma unroll
    for (int jj = 0; jj < 8; ++jj) {
      int h = ks * 32 + quad * 8 + jj;
      float a = W1[h], b = W1[NH + h];
      float z = fmaf(p, a, fmaf(t, b, b1[h]));
      float y = fast_tanh(z);
      float f1 = fmaf(-y, y, 1.0f);
      float f3 = f1 * fmaf(-6.0f, f1, 4.0f);
      float na = -2.0f * (y * f1);              // -2*y*f1 = true f2
      float a2 = a * a, ab = a * b, bb = b * b;
      float f3a2 = f3 * a2, f3bb = f3 * bb;
      float v1 = f1 * a, v2 = f1 * b;
      _Float16 yh = (_Float16)y;
      _Float16 v1h = (_Float16)v1;
      _Float16 v2h = (_Float16)v2;
      A0h[ks][jj] = yh;   A0l[ks][jj] = (_Float16)(y - (float)yh);
      A1h[ks][jj] = v1h;  A1l[ks][jj] = (_Float16)(v1 - (float)v1h);
      A2h[ks][jj] = v2h;  A2l[ks][jj] = (_Float16)(v2 - (float)v2h);
      A3[ks][jj] = (_Float16)(na * a2);
      A4[ks][jj] = (_Float16)(na * ab);
      A5[ks][jj] = (_Float16)(na * bb);
      A6[ks][jj] = (_Float16)(f3a2 * a);
      A7[ks][jj] = (_Float16)(f3a2 * b);
      A8[ks][jj] = (_Float16)(f3bb * a);
      A9[ks][jj] = (_Float16)(f3bb * b);
    }
  }

  float4v Tacc[9];
#pragma unroll
  for (int x = 0; x < 9; ++x) Tacc[x] = (float4v){0.f, 0.f, 0.f, 0.f};

#pragma unroll
  for (int nt = 0; nt < 4; ++nt) {
    float4v acc[10];
#pragma unroll
    for (int k = 0; k < 10; ++k) acc[k] = (float4v){0.f, 0.f, 0.f, 0.f};
#pragma unroll
    for (int ks = 0; ks < 2; ++ks) {
      half8 bh = ldB(Bws, 0, nt, ks, lane);
      half8 bl = ldB(Bws, 1, nt, ks, lane);
      acc[0] = __builtin_amdgcn_mfma_f32_16x16x32_f16(A0h[ks], bh, acc[0], 0, 0, 0);
      acc[0] = __builtin_amdgcn_mfma_f32_16x16x32_f16(A0l[ks], bh, acc[0], 0, 0, 0);
      acc[0] = __builtin_amdgcn_mfma_f32_16x16x32_f16(A0h[ks], bl, acc[0], 0, 0, 0);
      acc[1] = __builtin_amdgcn_mfma_f32_16x16x32_f16(A1h[ks], bh, acc[1], 0, 0, 0);
      acc[1] = __builtin_amdgcn_mfma_f32_16x16x32_f16(A1l[ks], bh, acc[1], 0, 0, 0);
      acc[1] = __builtin_amdgcn_mfma_f32_16x16x32_f16(A1h[ks], bl, acc[1], 0, 0, 0);
      acc[2] = __builtin_amdgcn_mfma_f32_16x16x32_f16(A2h[ks], bh, acc[2], 0, 0, 0);
      acc[2] = __builtin_amdgcn_mfma_f32_16x16x32_f16(A2l[ks], bh, acc[2], 0, 0, 0);
      acc[2] = __builtin_amdgcn_mfma_f32_16x16x32_f16(A2h[ks], bl, acc[2], 0, 0, 0);
      acc[3] = __builtin_amdgcn_mfma_f32_16x16x32_f16(A3[ks], bh, acc[3], 0, 0, 0);
      acc[4] = __builtin_amdgcn_mfma_f32_16x16x32_f16(A4[ks], bh, acc[4], 0, 0, 0);
      acc[5] = __builtin_amdgcn_mfma_f32_16x16x32_f16(A5[ks], bh, acc[5], 0, 0, 0);
      acc[6] = __builtin_amdgcn_mfma_f32_16x16x32_f16(A6[ks], bh, acc[6], 0, 0, 0);
      acc[7] = __builtin_amdgcn_mfma_f32_16x16x32_f16(A7[ks], bh, acc[7], 0, 0, 0);
      acc[8] = __builtin_amdgcn_mfma_f32_16x16x32_f16(A8[ks], bh, acc[8], 0, 0, 0);
      acc[9] = __builtin_amdgcn_mfma_f32_16x16x32_f16(A9[ks], bh, acc[9], 0, 0, 0);
    }
    // ---- Faa di Bruno + W3 on C-layout: lane holds (point=quad*4+r, j=nt*16+col) ----
    float b2v = b2[nt * 16 + col];
    float w3v = W3[nt * 16 + col];
#pragma unroll
    for (int r = 0; r < 4; ++r) {
      float z0 = acc[0][r] + b2v;
      float y2 = fast_tanh(z0);
      float g1 = fmaf(-y2, y2, 1.0f);
      float g2 = -2.0f * (y2 * g1);
      float g3 = g1 * fmaf(-6.0f, g1, 4.0f);
      float gp = acc[1][r], gt = acc[2][r];
      float gpp = acc[3][r], gpt = acc[4][r], gtt = acc[5][r];
      float zppp = acc[6][r], zppt = acc[7][r], zptt = acc[8][r], zttt = acc[9][r];
      float gp2 = gp * gp, gt2 = gt * gt;
      Tacc[0][r] = fmaf(w3v, g1 * gp, Tacc[0][r]);
      Tacc[1][r] = fmaf(w3v, g1 * gt, Tacc[1][r]);
      Tacc[2][r] = fmaf(w3v, fmaf(g2, gp2, g1 * gpp), Tacc[2][r]);
      Tacc[3][r] = fmaf(w3v, fmaf(g2, gp * gt, g1 * gpt), Tacc[3][r]);
      Tacc[4][r] = fmaf(w3v, fmaf(g2, gt2, g1 * gtt), Tacc[4][r]);
      Tacc[5][r] = fmaf(w3v, fmaf(g3, gp2 * gp, fmaf(3.0f * g2, gp * gpp, g1 * zppp)), Tacc[5][r]);
      Tacc[6][r] = fmaf(w3v, fmaf(g3, gp2 * gt, fmaf(g2, fmaf(2.0f, gp * gpt, gt * gpp), g1 * zppt)), Tacc[6][r]);
      Tacc[7][r] = fmaf(w3v, fmaf(g3, gp * gt2, fmaf(g2, fmaf(2.0f, gt * gpt, gp * gtt), g1 * zptt)), Tacc[7][r]);
      Tacc[8][r] = fmaf(w3v, fmaf(g3, gt2 * gt, fmaf(3.0f * g2, gt * gtt, g1 * zttt)), Tacc[8][r]);
    }
  }

  // ---- fold-butterfly reduce over the 16 cols ----
  // Step 1 (xor 8) folds the r0/r1-vs-r2/r3 selection into the exchange;
  // step 2 (xor 4) folds r-within-pair; steps 3-4 finish the sum.
  // Result: lane col holds T_x for r = col>>2 (4 identical copies per r);
  // (col&3)==0 lanes store.  Half the ops of the full 4x4 butterfly, and
  // the old per-lane rsel select disappears.
  float T[9];
#pragma unroll
  for (int x = 0; x < 9; ++x) {
    float4v v = Tacc[x];
    bool hi8 = (col & 8) != 0;
    float k0 = hi8 ? v[2] : v[0];
    float k1 = hi8 ? v[3] : v[1];
    float s0 = hi8 ? v[0] : v[2];
    float s1 = hi8 ? v[1] : v[3];
    float p0 = k0 + __shfl_xor(s0, 8, 16);
    float p1 = k1 + __shfl_xor(s1, 8, 16);
    bool hi4 = (col & 4) != 0;
    float kk = hi4 ? p1 : p0;
    float ss = hi4 ? p0 : p1;
    float q = kk + __shfl_xor(ss, 4, 16);
    q += __shfl_xor(q, 2, 16);
    q += __shfl_xor(q, 1, 16);
    T[x] = q;
  }
  float Tp = T[0], Tt = T[1], Tpp = T[2], Tpt = T[3], Ttt = T[4];
  float Tppp = T[5], Tppt = T[6], Tptt = T[7], Tttt = T[8];

  int rsel = col >> 2;
  int pi = pbase + quad * 4 + rsel;
  float t2 = theta[pi];
  float s, c;
  __sincosf(t2, &s, &c);
  float inv_s = __builtin_amdgcn_rcpf(s);
  float inv_s2 = inv_s * inv_s;

  float A = Tp * inv_s + Tt;          // u_theta
  float D = Tp * inv_s - Tt;          // u_phi
  float q1 = Tpt * inv_s - Tp * c * inv_s2;
  float A_t = q1 + Ttt;
  float D_t = q1 - Ttt;
  float q2 = Tptt * inv_s - 2.0f * Tpt * c * inv_s2
           + Tp * (s * s + 2.0f * c * c) * inv_s2 * inv_s;
  float A_tt = q2 + Tttt;
  float D_tt = q2 - Tttt;
  float A_pp = Tppp * inv_s + Tppt;
  float D_p  = Tpp * inv_s - Tpt;
  float D_pp = Tppp * inv_s - Tppt;

  float utt   = -(A_t * s + A * c);
  float uttt  = -(A_tt * s + 2.0f * A_t * c - A * s) * s + utt * c;
  float utpp  = -A_pp;
  float upht  = D_t * s + D * c;
  float uphtt = (D_tt * s + 2.0f * D_t * c - D * s) * s + upht * c;
  float upp   = D_p;
  float uppp  = D_pp;

  float r = radius[pi];
  float inv_r = __builtin_amdgcn_rcpf(r);
  float inv_r2 = inv_r * inv_r;
  float div_uh = (utt + upp) * inv_r * inv_s;
  float lap_t = s * inv_r2 * uttt + utpp * inv_s2 * inv_r2;
  float lap_p = s * inv_r2 * uphtt + uppp * inv_s2 * inv_r2;
  float comp = s * (lap_t * lap_t + lap_p * lap_p);
  float sv = -(A * hth[pi] + D * hph[pi]) - br[pi] * div_uh;
  float tg = div_uh - A * s * __builtin_amdgcn_rcpf(c) * inv_r;

  if ((col & 3) == 0) {
    out[pi]         = A;
    out[n + pi]     = D;
    out[2 * n + pi] = div_uh;
    out[3 * n + pi] = sv;
    out[4 * n + pi] = tg;
    out[5 * n + pi] = comp;
  }
}

extern "C" void kernel_launch(void* const* d_in, const int* in_sizes, int n_in,
                              void* d_out, int out_size, void* d_ws, size_t ws_size,
                              hipStream_t stream) {
  const float* phi    = (const float*)d_in[0];
  const float* theta  = (const float*)d_in[1];
  const float* radius = (const float*)d_in[2];
  const float* hth    = (const float*)d_in[3];
  const float* hph    = (const float*)d_in[4];
  const float* br     = (const float*)d_in[5];
  const float* W1     = (const float*)d_in[6];
  const float* b1     = (const float*)d_in[7];
  const float* W2     = (const float*)d_in[8];
  const float* b2     = (const float*)d_in[9];
  const float* W3     = (const float*)d_in[10];
  (void)ws_size; (void)n_in; (void)out_size;

  _Float16* Bws = (_Float16*)d_ws;     // 2 slots * 4 nt * 2 ks * 512 halfs = 16 KB
  float* out = (float*)d_out;
  int n = in_sizes[0];

  prep_B<<<(2 * 4096 + 255) / 256, 256, 0, stream>>>(W2, Bws);
  int ntiles = (n + 15) / 16;
  int nblocks = (ntiles + 3) / 4;
  pinn_mfma<<<nblocks, 256, 0, stream>>>(
      phi, theta, radius, hth, hph, br, W1, b1, b2, W3, Bws, out, n);
}